// Round 19
// baseline (62.938 us; speedup 1.0000x reference)
//
#include <hip/hip_runtime.h>
#include <hip/hip_bf16.h>

// Interpolate1D: z = interp(cumsum(softmax(x@W + b)), y); outputs (z[B], x[B,64], logdet[B]+log|slope|)
// B=524288, D=64, R=256.
//
// Round-19 = round-18 (59.5us: r11 + nt passthrough stores) + three bundled changes:
//  1. W pre-packed to d_ws by a tiny pack kernel (r12-verified layout); main kernel
//     fills sW with a 4-instruction u32x4 copy (no per-block convert/layout VALU,
//     no serial no-HBM startup phase).
//  2. nt on z/logdet stores too (never re-read; contiguous -> no write amplification).
//  3. Grid 2048x512, 2 tiles/wave: pack is now ~free per block, so oversubscribing
//     (8 blocks/CU queued vs 4 resident) backfills retiring blocks through the tail.
// r18 postmortem: nt passthrough won 8% but NOT via the predicted L3 mechanism
// (FETCH unchanged 68MB; WRITE rose 135->155 = partial-line amplification). Real
// mechanism: less L2 pollution -> lower x-load latency. Cache model demoted.
// Kept: fused n-loop, swapped MFMA operands, register prefetch, LICM fence, log2e
// pre-scale + exp2, float-mask prefix sums, branchless searchsorted, v_perm-free
// truncating pack. Assumes ws_size >= 33KB.

#define NB 524288
#define NWT (NB / 16)   // 32768 wave-tiles of 16 rows

typedef __attribute__((ext_vector_type(4))) float f32x4;
typedef __attribute__((ext_vector_type(4))) unsigned int u32x4;
typedef __attribute__((ext_vector_type(8))) __bf16 bf16x8;

#define LOG2E 1.4426950408889634f

static __device__ __forceinline__ unsigned short f2b(float f) {
    unsigned u = __builtin_bit_cast(unsigned, f);
    u += 0x7fffu + ((u >> 16) & 1u);          // RNE (pack kernel only)
    return (unsigned short)(u >> 16);
}
static __device__ __forceinline__ unsigned pk2t(float a, float b) {
    // truncating bf16x2 pack: hi16(a) | hi16(b)
    return (__builtin_bit_cast(unsigned, a) >> 16) | (__builtin_bit_cast(unsigned, b) & 0xffff0000u);
}

// --- pack kernel: W*log2e -> bf16 MFMA-frag layout in d_ws; bias*log2e appended ---
__global__ __launch_bounds__(256) void pack_kernel(
    const float* __restrict__ W, const float* __restrict__ bias,
    unsigned short* __restrict__ wpack, float* __restrict__ bpack)
{
    const int k = blockIdx.x;       // 64 blocks: one W row each
    const int t = threadIdx.x;      // W column
    float wv = W[k * 256 + t] * LOG2E;
    int lane16 = ((k >> 3) & 3) * 16 + (t & 15);
    int n = t >> 4, kb = k >> 5, i = k & 7;
    wpack[((kb * 16 + n) * 64 + lane16) * 8 + i] = f2b(wv);
    if (k == 0) bpack[t] = bias[t] * LOG2E;
}

__global__ __launch_bounds__(512, 4) void interp1d_kernel(
    const float* __restrict__ y, const float* __restrict__ x,
    const unsigned short* __restrict__ wpack, const float* __restrict__ bpack,
    const float* __restrict__ logdet, const float* __restrict__ bp,
    float* __restrict__ out)
{
    __shared__ unsigned short sW[2 * 16 * 64 * 8];   // 32KB, frag layout (pre-packed)
    __shared__ float sBP[256];
    __shared__ float sBias[256];

    const int t = threadIdx.x;

    // --- fast LDS fill: 2048 u32x4 units, 512 threads x 4 (no converts, no layout math) ---
    if (t < 256) {
        sBP[t]   = bp[t];
        sBias[t] = bpack[t];
    }
    {
        const u32x4* src = reinterpret_cast<const u32x4*>(wpack);
        u32x4* dst = reinterpret_cast<u32x4*>(sW);
        #pragma unroll
        for (int j = 0; j < 4; ++j) dst[j * 512 + t] = src[j * 512 + t];
    }
    __syncthreads();

    const int lane = t & 63;
    const int colb = lane & 15;     // this lane's x-row within the tile (C column)
    const int kH   = lane >> 4;     // 0..3: k-half for frags; C row group (cols kH*4+j)
    const int nw   = gridDim.x << 3;            // 8 waves per block

    int wt = (blockIdx.x << 3) | (t >> 6);

    // --- preload first tile ---
    f32x4 v0 = {}, v1 = {}, v2 = {}, v3 = {};
    float yv = 0.f, ldv = 0.f;
    if (wt < NWT) {
        const float* xr = x + (size_t)((wt << 4) + colb) * 64 + (kH << 3);
        v0 = *reinterpret_cast<const f32x4*>(xr);
        v1 = *reinterpret_cast<const f32x4*>(xr + 4);
        v2 = *reinterpret_cast<const f32x4*>(xr + 32);
        v3 = *reinterpret_cast<const f32x4*>(xr + 36);
        yv  = y[(wt << 4) + colb];
        ldv = logdet[(wt << 4) + colb];
    }

    for (; wt < NWT; wt += nw) {
        const int m0 = wt << 4;
        const int wtn = wt + nw;

        // --- prefetch next tile (latency hidden under this tile's compute) ---
        f32x4 n0 = {}, n1 = {}, n2 = {}, n3 = {};
        float yn = 0.f, ldn = 0.f;
        if (wtn < NWT) {
            const float* xr = x + (size_t)((wtn << 4) + colb) * 64 + (kH << 3);
            n0 = *reinterpret_cast<const f32x4*>(xr);
            n1 = *reinterpret_cast<const f32x4*>(xr + 4);
            n2 = *reinterpret_cast<const f32x4*>(xr + 32);
            n3 = *reinterpret_cast<const f32x4*>(xr + 36);
            yn  = y[(wtn << 4) + colb];
            ldn = logdet[(wtn << 4) + colb];
        }

        // compiler fence: keep sW ds_reads inside the tile loop (r3 LICM lesson)
        asm volatile("" ::: "memory");

        // --- passthrough x store: non-temporal (r18 win: less L2 pollution) ---
        float* xo = out + NB + (size_t)(m0 + colb) * 64 + (kH << 3);
        __builtin_nontemporal_store(v0, reinterpret_cast<f32x4*>(xo));
        __builtin_nontemporal_store(v1, reinterpret_cast<f32x4*>(xo + 4));
        __builtin_nontemporal_store(v2, reinterpret_cast<f32x4*>(xo + 32));
        __builtin_nontemporal_store(v3, reinterpret_cast<f32x4*>(xo + 36));

        // --- pack x into B-fragment (col = x-row = lane&15, k = kH*8+i) ---
        u32x4 pa, pb;
        pa[0] = pk2t(v0[0], v0[1]); pa[1] = pk2t(v0[2], v0[3]);
        pa[2] = pk2t(v1[0], v1[1]); pa[3] = pk2t(v1[2], v1[3]);
        pb[0] = pk2t(v2[0], v2[1]); pb[1] = pk2t(v2[2], v2[3]);
        pb[2] = pk2t(v3[0], v3[1]); pb[3] = pk2t(v3[2], v3[3]);
        bf16x8 a0 = __builtin_bit_cast(bf16x8, pa);
        bf16x8 a1 = __builtin_bit_cast(bf16x8, pb);

        // --- searchsorted (branchless: bp ~ linspace so guess is off by <= 1) ---
        int s = (int)floorf(yv * 255.0f);
        s = min(254, max(0, s));
        s += (sBP[s + 1] <= yv) ? 1 : 0;   // bp[255]=1.0 > yv, can't reach 255
        s = min(s, 254);
        s -= (sBP[s] > yv) ? 1 : 0;
        s = max(s, 0);

        // --- per-lane float masks for the partial blocks ---
        const int sb  = s >> 4,  so  = s & 15;            // block/offset of s
        const int sb1 = (s + 1) >> 4, so1 = (s + 1) & 15; // block/offset of s+1
        float m[4], pm[4];
        #pragma unroll
        for (int j = 0; j < 4; ++j) {
            m[j]  = ((kH << 2) + j <= so)  ? 1.f : 0.f;
            pm[j] = ((kH << 2) + j == so1) ? 1.f : 0.f;
        }

        // --- FUSED n-loop: MFMA (transient c) -> exp2 -> masked sums ---
        float denom = 0.f, f0s = 0.f, p1 = 0.f;
        #pragma unroll
        for (int n = 0; n < 16; ++n) {
            bf16x8 w0 = *reinterpret_cast<const bf16x8*>(&sW[(n * 64 + lane) * 8]);
            bf16x8 w1 = *reinterpret_cast<const bf16x8*>(&sW[((16 + n) * 64 + lane) * 8]);
            f32x4 c = *reinterpret_cast<const f32x4*>(&sBias[(n << 4) + (kH << 2)]);
            c = __builtin_amdgcn_mfma_f32_16x16x32_bf16(w0, a0, c, 0, 0, 0);
            c = __builtin_amdgcn_mfma_f32_16x16x32_bf16(w1, a1, c, 0, 0, 0);
            float e0 = __builtin_amdgcn_exp2f(c[0]);
            float e1 = __builtin_amdgcn_exp2f(c[1]);
            float e2 = __builtin_amdgcn_exp2f(c[2]);
            float e3 = __builtin_amdgcn_exp2f(c[3]);
            float bs = (e0 + e1) + (e2 + e3);
            denom += bs;
            float t0 = fmaf(e3, m[3], fmaf(e2, m[2], fmaf(e1, m[1], e0 * m[0])));
            float tp = fmaf(e3, pm[3], fmaf(e2, pm[2], fmaf(e1, pm[1], e0 * pm[0])));
            f0s += (n < sb) ? bs : ((n == sb) ? t0 : 0.f);
            p1  += (n == sb1) ? tp : 0.f;
        }

        // --- reduce over the 4 kH lanes sharing this x-row ---
        denom += __shfl_xor(denom, 16, 64);
        f0s   += __shfl_xor(f0s,   16, 64);
        p1    += __shfl_xor(p1,    16, 64);
        denom += __shfl_xor(denom, 32, 64);
        f0s   += __shfl_xor(f0s,   32, 64);
        p1    += __shfl_xor(p1,    32, 64);

        if (kH == 0) {   // lanes 0..15 store rows m0..m0+15: contiguous 64B
            float x0 = sBP[s], x1 = sBP[s + 1];
            float inv = 1.0f / denom;
            float f0 = f0s * inv;
            float slope = (p1 * inv) / (x1 - x0);
            __builtin_nontemporal_store(fmaf(slope, yv - x0, f0), out + m0 + colb);
            __builtin_nontemporal_store(ldv + __logf(fabsf(slope)),
                                        out + (size_t)NB * 65 + m0 + colb);
        }

        // --- rotate prefetched tile in ---
        if (wtn < NWT) {
            v0 = n0; v1 = n1; v2 = n2; v3 = n3;
            yv = yn; ldv = ldn;
        }
    }
}

extern "C" void kernel_launch(void* const* d_in, const int* in_sizes, int n_in,
                              void* d_out, int out_size, void* d_ws, size_t ws_size,
                              hipStream_t stream) {
    (void)in_sizes; (void)n_in; (void)out_size; (void)ws_size;
    const float* y      = (const float*)d_in[0];
    const float* x      = (const float*)d_in[1];
    const float* W      = (const float*)d_in[2];
    const float* b      = (const float*)d_in[3];
    const float* logdet = (const float*)d_in[4];
    const float* bp     = (const float*)d_in[5];
    float* out = (float*)d_out;

    unsigned short* wpack = (unsigned short*)d_ws;            // 32KB frag-layout bf16 W
    float* bpack = (float*)((char*)d_ws + 32768);             // 1KB bias*log2e

    pack_kernel<<<dim3(64), dim3(256), 0, stream>>>(W, b, wpack, bpack);
    // 2048 blocks x 512 thr, 2 tiles/wave: LDS-resident 4 blocks/CU, queued blocks
    // backfill as waves retire (pack per block is now a 4-instruction copy).
    interp1d_kernel<<<dim3(2048), dim3(512), 0, stream>>>(y, x, wpack, bpack, logdet, bp, out);
}

// Round 20
// 59.588 us; speedup vs baseline: 1.0562x; 1.0562x over previous
//
#include <hip/hip_runtime.h>
#include <hip/hip_bf16.h>

// Interpolate1D: z = interp(cumsum(softmax(x@W + b)), y); outputs (z[B], x[B,64], logdet[B]+log|slope|)
// B=524288, D=64, R=256.
//
// Round-20 = round-18 (best: 59.5us) + ONE isolated change: non-temporal z/logdet
// stores (contiguous 64B/16-lane groups, never re-read -> no amplification risk,
// keeps output streams out of L2 like the r18 passthrough win).
// r19 postmortem: the 3-way bundle (pre-pack kernel + LDS refill + 2048 blocks)
// regressed to 62.9 — extra dispatch + 64MB of per-block wpack L2 reads + 2x block
// starts outweighed the removed pack VALU. Reverted wholesale.
// Everything else byte-identical to r18 (r11 body: fused n-loop, 512-thr blocks,
// swapped MFMA operands, register prefetch, LICM fence, log2e pre-scale + exp2,
// float-mask prefix sums, branchless searchsorted, nt passthrough stores).

#define NB 524288
#define NWT (NB / 16)   // 32768 wave-tiles of 16 rows

typedef __attribute__((ext_vector_type(4))) float f32x4;
typedef __attribute__((ext_vector_type(4))) unsigned int u32x4;
typedef __attribute__((ext_vector_type(8))) __bf16 bf16x8;

#define LOG2E 1.4426950408889634f

static __device__ __forceinline__ unsigned short f2b(float f) {
    unsigned u = __builtin_bit_cast(unsigned, f);
    u += 0x7fffu + ((u >> 16) & 1u);          // RNE (W pack only; one-time)
    return (unsigned short)(u >> 16);
}
static __device__ __forceinline__ unsigned pk2t(float a, float b) {
    // truncating bf16x2 pack: hi16(a) | hi16(b)
    return (__builtin_bit_cast(unsigned, a) >> 16) | (__builtin_bit_cast(unsigned, b) & 0xffff0000u);
}

__global__ __launch_bounds__(512, 4) void interp1d_kernel(
    const float* __restrict__ y, const float* __restrict__ x,
    const float* __restrict__ W, const float* __restrict__ bias,
    const float* __restrict__ logdet, const float* __restrict__ bp,
    float* __restrict__ out)
{
    __shared__ unsigned short sW[2 * 16 * 64 * 8];   // 32KB, [kb][n][lane][i] frag layout
    __shared__ float sBP[256];
    __shared__ float sBias[256];                     // pre-scaled by log2e

    const int t = threadIdx.x;

    // --- once per block: bp, bias*log2e, W*log2e packed into MFMA fragment layout ---
    if (t < 256) {
        sBP[t]   = bp[t];
        sBias[t] = bias[t] * LOG2E;
    }
    {
        const int col = t & 255;
        const int k0  = (t >> 8) << 5;
        const int lane16lo = col & 15;
        const int n = col >> 4;
        for (int kk = 0; kk < 32; ++kk) {
            int k = k0 + kk;
            float wv = W[k * 256 + col] * LOG2E;      // coalesced within each 256-thread half
            int lane16 = ((k >> 3) & 3) * 16 + lane16lo;
            int kb = k >> 5, i = k & 7;
            sW[((kb * 16 + n) * 64 + lane16) * 8 + i] = f2b(wv);
        }
    }
    __syncthreads();

    const int lane = t & 63;
    const int colb = lane & 15;     // this lane's x-row within the tile (C column)
    const int kH   = lane >> 4;     // 0..3: k-half for frags; C row group (cols kH*4+j)
    const int nw   = gridDim.x << 3;            // 8 waves per block

    int wt = (blockIdx.x << 3) | (t >> 6);

    // --- preload first tile ---
    f32x4 v0 = {}, v1 = {}, v2 = {}, v3 = {};
    float yv = 0.f, ldv = 0.f;
    if (wt < NWT) {
        const float* xr = x + (size_t)((wt << 4) + colb) * 64 + (kH << 3);
        v0 = *reinterpret_cast<const f32x4*>(xr);
        v1 = *reinterpret_cast<const f32x4*>(xr + 4);
        v2 = *reinterpret_cast<const f32x4*>(xr + 32);
        v3 = *reinterpret_cast<const f32x4*>(xr + 36);
        yv  = y[(wt << 4) + colb];
        ldv = logdet[(wt << 4) + colb];
    }

    for (; wt < NWT; wt += nw) {
        const int m0 = wt << 4;
        const int wtn = wt + nw;

        // --- prefetch next tile (latency hidden under this tile's compute) ---
        f32x4 n0 = {}, n1 = {}, n2 = {}, n3 = {};
        float yn = 0.f, ldn = 0.f;
        if (wtn < NWT) {
            const float* xr = x + (size_t)((wtn << 4) + colb) * 64 + (kH << 3);
            n0 = *reinterpret_cast<const f32x4*>(xr);
            n1 = *reinterpret_cast<const f32x4*>(xr + 4);
            n2 = *reinterpret_cast<const f32x4*>(xr + 32);
            n3 = *reinterpret_cast<const f32x4*>(xr + 36);
            yn  = y[(wtn << 4) + colb];
            ldn = logdet[(wtn << 4) + colb];
        }

        // compiler fence: stop LICM from hoisting sW ds_reads out of the tile loop (r3 lesson)
        asm volatile("" ::: "memory");

        // --- passthrough x store: NON-TEMPORAL (r18 win: keeps write stream out of L2) ---
        float* xo = out + NB + (size_t)(m0 + colb) * 64 + (kH << 3);
        __builtin_nontemporal_store(v0, reinterpret_cast<f32x4*>(xo));
        __builtin_nontemporal_store(v1, reinterpret_cast<f32x4*>(xo + 4));
        __builtin_nontemporal_store(v2, reinterpret_cast<f32x4*>(xo + 32));
        __builtin_nontemporal_store(v3, reinterpret_cast<f32x4*>(xo + 36));

        // --- pack x into B-fragment (col = x-row = lane&15, k = kH*8+i) ---
        u32x4 pa, pb;
        pa[0] = pk2t(v0[0], v0[1]); pa[1] = pk2t(v0[2], v0[3]);
        pa[2] = pk2t(v1[0], v1[1]); pa[3] = pk2t(v1[2], v1[3]);
        pb[0] = pk2t(v2[0], v2[1]); pb[1] = pk2t(v2[2], v2[3]);
        pb[2] = pk2t(v3[0], v3[1]); pb[3] = pk2t(v3[2], v3[3]);
        bf16x8 a0 = __builtin_bit_cast(bf16x8, pa);
        bf16x8 a1 = __builtin_bit_cast(bf16x8, pb);

        // --- searchsorted (branchless: bp ~ linspace so guess is off by <= 1) ---
        int s = (int)floorf(yv * 255.0f);
        s = min(254, max(0, s));
        s += (sBP[s + 1] <= yv) ? 1 : 0;   // bp[255]=1.0 > yv, can't reach 255
        s = min(s, 254);
        s -= (sBP[s] > yv) ? 1 : 0;
        s = max(s, 0);

        // --- per-lane float masks for the partial blocks ---
        const int sb  = s >> 4,  so  = s & 15;            // block/offset of s
        const int sb1 = (s + 1) >> 4, so1 = (s + 1) & 15; // block/offset of s+1
        float m[4], pm[4];
        #pragma unroll
        for (int j = 0; j < 4; ++j) {
            m[j]  = ((kH << 2) + j <= so)  ? 1.f : 0.f;
            pm[j] = ((kH << 2) + j == so1) ? 1.f : 0.f;
        }

        // --- FUSED n-loop: MFMA (transient c) -> exp2 -> masked sums ---
        float denom = 0.f, f0s = 0.f, p1 = 0.f;
        #pragma unroll
        for (int n = 0; n < 16; ++n) {
            bf16x8 w0 = *reinterpret_cast<const bf16x8*>(&sW[(n * 64 + lane) * 8]);
            bf16x8 w1 = *reinterpret_cast<const bf16x8*>(&sW[((16 + n) * 64 + lane) * 8]);
            f32x4 c = *reinterpret_cast<const f32x4*>(&sBias[(n << 4) + (kH << 2)]);
            c = __builtin_amdgcn_mfma_f32_16x16x32_bf16(w0, a0, c, 0, 0, 0);
            c = __builtin_amdgcn_mfma_f32_16x16x32_bf16(w1, a1, c, 0, 0, 0);
            float e0 = __builtin_amdgcn_exp2f(c[0]);
            float e1 = __builtin_amdgcn_exp2f(c[1]);
            float e2 = __builtin_amdgcn_exp2f(c[2]);
            float e3 = __builtin_amdgcn_exp2f(c[3]);
            float bs = (e0 + e1) + (e2 + e3);
            denom += bs;
            float t0 = fmaf(e3, m[3], fmaf(e2, m[2], fmaf(e1, m[1], e0 * m[0])));
            float tp = fmaf(e3, pm[3], fmaf(e2, pm[2], fmaf(e1, pm[1], e0 * pm[0])));
            f0s += (n < sb) ? bs : ((n == sb) ? t0 : 0.f);
            p1  += (n == sb1) ? tp : 0.f;
        }

        // --- reduce over the 4 kH lanes sharing this x-row ---
        denom += __shfl_xor(denom, 16, 64);
        f0s   += __shfl_xor(f0s,   16, 64);
        p1    += __shfl_xor(p1,    16, 64);
        denom += __shfl_xor(denom, 32, 64);
        f0s   += __shfl_xor(f0s,   32, 64);
        p1    += __shfl_xor(p1,    32, 64);

        if (kH == 0) {   // lanes 0..15 store rows m0..m0+15: contiguous 64B -> nt safe
            float x0 = sBP[s], x1 = sBP[s + 1];
            float inv = 1.0f / denom;
            float f0 = f0s * inv;
            float slope = (p1 * inv) / (x1 - x0);
            __builtin_nontemporal_store(fmaf(slope, yv - x0, f0), out + m0 + colb);
            __builtin_nontemporal_store(ldv + __logf(fabsf(slope)),
                                        out + (size_t)NB * 65 + m0 + colb);
        }

        // --- rotate prefetched tile in ---
        if (wtn < NWT) {
            v0 = n0; v1 = n1; v2 = n2; v3 = n3;
            yv = yn; ldv = ldn;
        }
    }
}

extern "C" void kernel_launch(void* const* d_in, const int* in_sizes, int n_in,
                              void* d_out, int out_size, void* d_ws, size_t ws_size,
                              hipStream_t stream) {
    (void)in_sizes; (void)n_in; (void)out_size; (void)d_ws; (void)ws_size;
    const float* y      = (const float*)d_in[0];
    const float* x      = (const float*)d_in[1];
    const float* W      = (const float*)d_in[2];
    const float* b      = (const float*)d_in[3];
    const float* logdet = (const float*)d_in[4];
    const float* bp     = (const float*)d_in[5];
    float* out = (float*)d_out;
    // r18 config: 512-thr blocks (8 waves share one 32KB sW), 1024 blocks, 4 tiles/wave.
    interp1d_kernel<<<dim3(1024), dim3(512), 0, stream>>>(y, x, W, b, logdet, bp, out);
}